// Round 1
// baseline (628.274 us; speedup 1.0000x reference)
//
#include <hip/hip_runtime.h>

// Predictor: MLP3 (Linear+BN(train)+ReLU x2, Linear) -> LSTM(64), 1 cond step + 25 self-feed steps.
// B=16384, OUT=128 (x3 concat -> 384), HID=32, LSTM_H=64, NPRED=25. Output (B,25,64) fp32.

#define EPSV 1e-5f

__device__ __forceinline__ float rcp_f(float x) { return __builtin_amdgcn_rcpf(x); }
__device__ __forceinline__ float sigm(float x) { return rcp_f(1.f + __expf(-x)); }
__device__ __forceinline__ float tanh_fast(float x) {
    // tanh(x) = 1 - 2/(e^{2x}+1); exp->inf gives +1, exp->0 gives -1 (branch-free, saturating)
    return 1.f - 2.f * rcp_f(__expf(2.f * x) + 1.f);
}

// ---------------- kernel 0: Wsum = Wih+Whh, bsum = bih+bhh ----------------
__global__ __launch_bounds__(256) void k_wsum(const float* __restrict__ Wih,
                                              const float* __restrict__ Whh,
                                              const float* __restrict__ bih,
                                              const float* __restrict__ bhh,
                                              float* __restrict__ Wsum,
                                              float* __restrict__ bsum) {
    int i = blockIdx.x * 256 + threadIdx.x;
    if (i < 16384) Wsum[i] = Wih[i] + Whh[i];
    if (i < 256)   bsum[i] = bih[i] + bhh[i];
}

// ---------------- kernel 1: pre1 = [x0|x1|x2] @ W1^T + b1, + BN1 stats ----------------
// 256 blocks x 256 threads; block = 64 rows; wave w handles k-slice [w*96, w*96+96)
__global__ __launch_bounds__(256) void k_mlp1(const float* __restrict__ x0,
                                              const float* __restrict__ x1,
                                              const float* __restrict__ x2,
                                              const float* __restrict__ W1,
                                              const float* __restrict__ b1,
                                              float* __restrict__ pre1,
                                              float* __restrict__ stats1) {
    __shared__ __align__(16) float xs[64 * 388];   // 64 rows x 384 (stride 388)
    __shared__ __align__(16) float part[256 * 36]; // per-thread partials (stride 36)
    const int tid = threadIdx.x;
    const int r0  = blockIdx.x * 64;

    // stage x (coalesced): 3 arrays x (64 rows x 128 floats) = 2048 float4 each
    for (int a = 0; a < 3; ++a) {
        const float* xp = (a == 0) ? x0 : (a == 1) ? x1 : x2;
        const float4* src = (const float4*)(xp + (size_t)r0 * 128);
        #pragma unroll
        for (int it = 0; it < 8; ++it) {
            int gi  = it * 256 + tid;  // 0..2047
            int row = gi >> 5;         // 32 float4 per row
            int c4  = gi & 31;
            float4 v = src[gi];
            *(float4*)&xs[row * 388 + a * 128 + c4 * 4] = v;
        }
    }
    __syncthreads();

    const int r   = tid & 63;
    const int kqu = __builtin_amdgcn_readfirstlane(tid >> 6); // wave-uniform k-slice id
    const int kbase = kqu * 96;

    float acc[32];
    #pragma unroll
    for (int j = 0; j < 32; ++j) acc[j] = (kqu == 0) ? b1[j] : 0.f;

    for (int k4 = 0; k4 < 24; ++k4) {
        int k = kbase + k4 * 4;
        float4 xv = *(const float4*)&xs[r * 388 + k];
        #pragma unroll
        for (int j = 0; j < 32; ++j) {
            const float* w = W1 + j * 384 + k; // wave-uniform -> s_load
            acc[j] += xv.x * w[0] + xv.y * w[1] + xv.z * w[2] + xv.w * w[3];
        }
    }
    #pragma unroll
    for (int j = 0; j < 32; ++j) part[tid * 36 + j] = acc[j];
    __syncthreads();

    if (tid < 64) {
        float fin[32];
        #pragma unroll
        for (int j = 0; j < 32; ++j)
            fin[j] = part[tid * 36 + j] + part[(64 + tid) * 36 + j] +
                     part[(128 + tid) * 36 + j] + part[(192 + tid) * 36 + j];
        float4* dst = (float4*)(pre1 + (size_t)(r0 + tid) * 32);
        #pragma unroll
        for (int j4 = 0; j4 < 8; ++j4)
            dst[j4] = make_float4(fin[j4 * 4 + 0], fin[j4 * 4 + 1], fin[j4 * 4 + 2], fin[j4 * 4 + 3]);
        #pragma unroll
        for (int j = 0; j < 32; ++j) part[tid * 36 + j] = fin[j];
    }
    __syncthreads();
    if (tid < 32) {
        float s = 0.f, sq = 0.f;
        for (int rr = 0; rr < 64; ++rr) {
            float v = part[rr * 36 + tid];
            s += v; sq += v * v;
        }
        atomicAdd(&stats1[tid], s);
        atomicAdd(&stats1[32 + tid], sq);
    }
}

// ---------------- kernel 2: h1 = relu(BN1(pre1)); pre2 = h1 @ W2^T + b2; BN2 stats ----------------
// 64 blocks x 256 threads, thread-per-row
__global__ __launch_bounds__(256) void k_mlp2(const float* __restrict__ pre1,
                                              const float* __restrict__ stats1,
                                              const float* __restrict__ g1,
                                              const float* __restrict__ be1,
                                              const float* __restrict__ W2,
                                              const float* __restrict__ b2,
                                              float* __restrict__ pre2,
                                              float* __restrict__ stats2) {
    __shared__ __align__(16) float t2[256 * 36];
    const int tid = threadIdx.x;
    const size_t r = (size_t)blockIdx.x * 256 + tid;
    const float invB = 1.f / 16384.f;

    float p[32];
    const float4* pr = (const float4*)(pre1 + r * 32);
    #pragma unroll
    for (int j4 = 0; j4 < 8; ++j4) {
        float4 v = pr[j4];
        p[j4 * 4 + 0] = v.x; p[j4 * 4 + 1] = v.y; p[j4 * 4 + 2] = v.z; p[j4 * 4 + 3] = v.w;
    }
    float h1[32];
    #pragma unroll
    for (int j = 0; j < 32; ++j) {
        float mu = stats1[j] * invB;
        float va = stats1[32 + j] * invB - mu * mu;
        float sc = g1[j] * rsqrtf(va + EPSV);
        float v  = (p[j] - mu) * sc + be1[j];
        h1[j] = fmaxf(v, 0.f);
    }
    float acc[32];
    #pragma unroll
    for (int j = 0; j < 32; ++j) {
        const float* w = W2 + j * 32;
        float a0 = 0.f, a1 = 0.f, a2 = 0.f, a3 = 0.f;
        #pragma unroll
        for (int k = 0; k < 32; k += 4) {
            a0 = fmaf(h1[k + 0], w[k + 0], a0);
            a1 = fmaf(h1[k + 1], w[k + 1], a1);
            a2 = fmaf(h1[k + 2], w[k + 2], a2);
            a3 = fmaf(h1[k + 3], w[k + 3], a3);
        }
        acc[j] = b2[j] + ((a0 + a1) + (a2 + a3));
    }
    float4* dst = (float4*)(pre2 + r * 32);
    #pragma unroll
    for (int j4 = 0; j4 < 8; ++j4)
        dst[j4] = make_float4(acc[j4 * 4 + 0], acc[j4 * 4 + 1], acc[j4 * 4 + 2], acc[j4 * 4 + 3]);

    #pragma unroll
    for (int j = 0; j < 32; ++j) t2[tid * 36 + j] = acc[j];
    __syncthreads();
    if (tid < 32) {
        float s = 0.f, sq = 0.f;
        for (int rr = 0; rr < 256; ++rr) {
            float v = t2[rr * 36 + tid];
            s += v; sq += v * v;
        }
        atomicAdd(&stats2[tid], s);
        atomicAdd(&stats2[32 + tid], sq);
    }
}

// ---------------- kernel 3: BN2 -> ReLU -> m = h2 @ W3^T + b3 -> LSTM 26 steps ----------------
// 256 blocks x 256 threads; block = 64 rows (1 block/CU); wave q computes gates [q*64, q*64+64)
__global__ __launch_bounds__(256) void k_lstm(const float* __restrict__ pre2,
                                              const float* __restrict__ stats2,
                                              const float* __restrict__ g2,
                                              const float* __restrict__ be2,
                                              const float* __restrict__ W3,
                                              const float* __restrict__ b3,
                                              const float* __restrict__ Wih,
                                              const float* __restrict__ Wsum,
                                              const float* __restrict__ bsum,
                                              float* __restrict__ out) {
    __shared__ __align__(16) float gl[64 * 260]; // gates: 64 rows x 256 (stride 260)
    __shared__ __align__(16) float hl[64 * 68];  // h:     64 rows x 64  (stride 68)
    const int tid = threadIdx.x;
    const int r   = tid & 63;
    const int qu  = __builtin_amdgcn_readfirstlane(tid >> 6); // wave id 0..3 (uniform)
    const int r0  = blockIdx.x * 64;
    const float invB = 1.f / 16384.f;

    // ---- MLP tail: BN2 + ReLU + Linear(32->64); thread computes m[u], u in [16q,16q+16)
    float p[32];
    {
        const float4* pr = (const float4*)(pre2 + (size_t)(r0 + r) * 32);
        #pragma unroll
        for (int j4 = 0; j4 < 8; ++j4) {
            float4 v = pr[j4];
            p[j4 * 4 + 0] = v.x; p[j4 * 4 + 1] = v.y; p[j4 * 4 + 2] = v.z; p[j4 * 4 + 3] = v.w;
        }
    }
    float h2[32];
    #pragma unroll
    for (int j = 0; j < 32; ++j) {
        float mu = stats2[j] * invB;
        float va = stats2[32 + j] * invB - mu * mu;
        float sc = g2[j] * rsqrtf(va + EPSV);
        float v  = (p[j] - mu) * sc + be2[j];
        h2[j] = fmaxf(v, 0.f);
    }
    #pragma unroll
    for (int uu = 0; uu < 16; ++uu) {
        int u = qu * 16 + uu;
        const float* w = W3 + u * 32; // uniform -> s_load
        float a0 = 0.f, a1 = 0.f, a2 = 0.f, a3 = 0.f;
        #pragma unroll
        for (int k = 0; k < 32; k += 4) {
            a0 = fmaf(h2[k + 0], w[k + 0], a0);
            a1 = fmaf(h2[k + 1], w[k + 1], a1);
            a2 = fmaf(h2[k + 2], w[k + 2], a2);
            a3 = fmaf(h2[k + 3], w[k + 3], a3);
        }
        hl[r * 68 + u] = b3[u] + ((a0 + a1) + (a2 + a3));
    }

    float c[16];
    #pragma unroll
    for (int uu = 0; uu < 16; ++uu) c[uu] = 0.f;
    __syncthreads();

    float h[64];
    #pragma unroll
    for (int k4 = 0; k4 < 16; ++k4) {
        float4 v = *(const float4*)&hl[r * 68 + k4 * 4];
        h[k4 * 4 + 0] = v.x; h[k4 * 4 + 1] = v.y; h[k4 * 4 + 2] = v.z; h[k4 * 4 + 3] = v.w;
    }

    const int ub = qu * 16;
    #pragma unroll 1
    for (int s = 0; s <= 25; ++s) {
        const float* Wp = (s == 0) ? Wih : Wsum; // step 0: h==0 so only Wih acts; else Wsum=Wih+Whh
        // ---- gates = h @ Wp^T + bsum, this wave's 64 gate columns
        #pragma unroll 1
        for (int grp = 0; grp < 8; ++grp) {
            int jb = qu * 64 + grp * 8;
            float accv[8];
            #pragma unroll
            for (int jj = 0; jj < 8; ++jj) {
                const float* wrow = Wp + (size_t)(jb + jj) * 64; // uniform -> s_load
                float a0 = 0.f, a1 = 0.f, a2 = 0.f, a3 = 0.f;
                #pragma unroll
                for (int k = 0; k < 64; k += 4) {
                    a0 = fmaf(h[k + 0], wrow[k + 0], a0);
                    a1 = fmaf(h[k + 1], wrow[k + 1], a1);
                    a2 = fmaf(h[k + 2], wrow[k + 2], a2);
                    a3 = fmaf(h[k + 3], wrow[k + 3], a3);
                }
                accv[jj] = bsum[jb + jj] + ((a0 + a1) + (a2 + a3));
            }
            *(float4*)&gl[r * 260 + jb]     = make_float4(accv[0], accv[1], accv[2], accv[3]);
            *(float4*)&gl[r * 260 + jb + 4] = make_float4(accv[4], accv[5], accv[6], accv[7]);
        }
        __syncthreads();

        // ---- activations + state update for u in [16q, 16q+16)
        #pragma unroll
        for (int u4 = 0; u4 < 4; ++u4) {
            float4 iv = *(const float4*)&gl[r * 260 + ub + u4 * 4];
            float4 fv = *(const float4*)&gl[r * 260 + 64 + ub + u4 * 4];
            float4 gv = *(const float4*)&gl[r * 260 + 128 + ub + u4 * 4];
            float4 ov = *(const float4*)&gl[r * 260 + 192 + ub + u4 * 4];
            float4 hn;
            {
                float cc = sigm(fv.x) * c[u4 * 4 + 0] + sigm(iv.x) * tanh_fast(gv.x);
                c[u4 * 4 + 0] = cc; hn.x = sigm(ov.x) * tanh_fast(cc);
            }
            {
                float cc = sigm(fv.y) * c[u4 * 4 + 1] + sigm(iv.y) * tanh_fast(gv.y);
                c[u4 * 4 + 1] = cc; hn.y = sigm(ov.y) * tanh_fast(cc);
            }
            {
                float cc = sigm(fv.z) * c[u4 * 4 + 2] + sigm(iv.z) * tanh_fast(gv.z);
                c[u4 * 4 + 2] = cc; hn.z = sigm(ov.z) * tanh_fast(cc);
            }
            {
                float cc = sigm(fv.w) * c[u4 * 4 + 3] + sigm(iv.w) * tanh_fast(gv.w);
                c[u4 * 4 + 3] = cc; hn.w = sigm(ov.w) * tanh_fast(cc);
            }
            *(float4*)&hl[r * 68 + ub + u4 * 4] = hn;
        }
        __syncthreads();

        // ---- write output (steps 1..25) + reload h registers
        if (s >= 1) {
            #pragma unroll
            for (int rep = 0; rep < 4; ++rep) {
                int fi = rep * 256 + tid;      // 0..1023 float4s
                int rr = fi >> 4, k4 = fi & 15;
                float4 v = *(const float4*)&hl[rr * 68 + k4 * 4];
                *(float4*)&out[(size_t)(r0 + rr) * 1600 + (size_t)(s - 1) * 64 + k4 * 4] = v;
            }
        }
        #pragma unroll
        for (int k4 = 0; k4 < 16; ++k4) {
            float4 v = *(const float4*)&hl[r * 68 + k4 * 4];
            h[k4 * 4 + 0] = v.x; h[k4 * 4 + 1] = v.y; h[k4 * 4 + 2] = v.z; h[k4 * 4 + 3] = v.w;
        }
    }
}

extern "C" void kernel_launch(void* const* d_in, const int* in_sizes, int n_in,
                              void* d_out, int out_size, void* d_ws, size_t ws_size,
                              hipStream_t stream) {
    const float* x0   = (const float*)d_in[0];
    const float* x1   = (const float*)d_in[1];
    const float* x2   = (const float*)d_in[2];
    const float* W1   = (const float*)d_in[3];
    const float* b1   = (const float*)d_in[4];
    const float* g1   = (const float*)d_in[5];
    const float* be1  = (const float*)d_in[6];
    const float* W2   = (const float*)d_in[7];
    const float* b2   = (const float*)d_in[8];
    const float* g2   = (const float*)d_in[9];
    const float* be2  = (const float*)d_in[10];
    const float* W3   = (const float*)d_in[11];
    const float* b3   = (const float*)d_in[12];
    const float* Wih  = (const float*)d_in[13];
    const float* Whh  = (const float*)d_in[14];
    const float* bih  = (const float*)d_in[15];
    const float* bhh  = (const float*)d_in[16];

    float* ws     = (float*)d_ws;
    float* pre1   = ws;                 // 524288 floats
    float* pre2   = ws + 524288;        // 524288 floats
    float* Wsum   = ws + 1048576;       // 16384
    float* bsum   = ws + 1064960;       // 256
    float* stats1 = ws + 1065216;       // 64
    float* stats2 = ws + 1065280;       // 64

    hipMemsetAsync(stats1, 0, 128 * sizeof(float), stream); // zero stats1+stats2 each call

    hipLaunchKernelGGL(k_wsum, dim3(64), dim3(256), 0, stream, Wih, Whh, bih, bhh, Wsum, bsum);
    hipLaunchKernelGGL(k_mlp1, dim3(256), dim3(256), 0, stream, x0, x1, x2, W1, b1, pre1, stats1);
    hipLaunchKernelGGL(k_mlp2, dim3(64), dim3(256), 0, stream, pre1, stats1, g1, be1, W2, b2, pre2, stats2);
    hipLaunchKernelGGL(k_lstm, dim3(256), dim3(256), 0, stream, pre2, stats2, g2, be2, W3, b3,
                       Wih, Wsum, bsum, (float*)d_out);
}

// Round 2
// 135.729 us; speedup vs baseline: 4.6289x; 4.6289x over previous
//
#include <hip/hip_runtime.h>

// Predictor: MLP3 (Linear+BN(train)+ReLU x2, Linear) -> LSTM(64), 1 cond step + 25 self-feed steps.
// B=16384, OUT=128 (x3 -> 384), HID=32, LSTM_H=64, NPRED=25. Output (B,25,64) fp32.
// LSTM via split-precision bf16 MFMA: gates = h_hi*W_hi + h_hi*W_lo + h_lo*W_hi (fp32 accum).

#define EPSV 1e-5f

typedef __attribute__((ext_vector_type(8))) short bf16x8;
typedef __attribute__((ext_vector_type(4))) float f32x4;

__device__ __forceinline__ float rcp_f(float x) { return __builtin_amdgcn_rcpf(x); }
__device__ __forceinline__ float sigm(float x) { return rcp_f(1.f + __expf(-x)); }
__device__ __forceinline__ float tanh_fast(float x) {
    // tanh(x) = 1 - 2/(e^{2x}+1); saturates correctly at +-1
    return 1.f - 2.f * rcp_f(__expf(2.f * x) + 1.f);
}
__device__ __forceinline__ void split_bf16(float x, ushort& hi, ushort& lo) {
    unsigned xb = __builtin_bit_cast(unsigned, x);
    hi = (ushort)(xb >> 16);
    float hif = __builtin_bit_cast(float, xb & 0xffff0000u);
    unsigned lb = __builtin_bit_cast(unsigned, x - hif);
    lo = (ushort)(lb >> 16);
}

// ---------------- kernel 0: split Wih and Wsum=Wih+Whh into bf16 hi/lo; bsum ----------------
__global__ __launch_bounds__(256) void k_prep(const float* __restrict__ Wih,
                                              const float* __restrict__ Whh,
                                              const float* __restrict__ bih,
                                              const float* __restrict__ bhh,
                                              ushort* __restrict__ Wih_hi,
                                              ushort* __restrict__ Wih_lo,
                                              ushort* __restrict__ Wsum_hi,
                                              ushort* __restrict__ Wsum_lo,
                                              float* __restrict__ bsum) {
    int i = blockIdx.x * 256 + threadIdx.x;
    if (i < 16384) {
        float wi = Wih[i];
        float ws = wi + Whh[i];
        ushort h, l;
        split_bf16(wi, h, l);
        Wih_hi[i] = h; Wih_lo[i] = l;
        split_bf16(ws, h, l);
        Wsum_hi[i] = h; Wsum_lo[i] = l;
    }
    if (i < 256) bsum[i] = bih[i] + bhh[i];
}

// ---------------- kernel 1: pre1 = [x0|x1|x2] @ W1^T + b1, + BN1 stats ----------------
__global__ __launch_bounds__(256) void k_mlp1(const float* __restrict__ x0,
                                              const float* __restrict__ x1,
                                              const float* __restrict__ x2,
                                              const float* __restrict__ W1,
                                              const float* __restrict__ b1,
                                              float* __restrict__ pre1,
                                              float* __restrict__ stats1) {
    __shared__ __align__(16) float xs[64 * 388];
    __shared__ __align__(16) float part[256 * 36];
    const int tid = threadIdx.x;
    const int r0  = blockIdx.x * 64;

    for (int a = 0; a < 3; ++a) {
        const float* xp = (a == 0) ? x0 : (a == 1) ? x1 : x2;
        const float4* src = (const float4*)(xp + (size_t)r0 * 128);
        #pragma unroll
        for (int it = 0; it < 8; ++it) {
            int gi  = it * 256 + tid;
            int row = gi >> 5;
            int c4  = gi & 31;
            float4 v = src[gi];
            *(float4*)&xs[row * 388 + a * 128 + c4 * 4] = v;
        }
    }
    __syncthreads();

    const int r   = tid & 63;
    const int kqu = __builtin_amdgcn_readfirstlane(tid >> 6);
    const int kbase = kqu * 96;

    float acc[32];
    #pragma unroll
    for (int j = 0; j < 32; ++j) acc[j] = (kqu == 0) ? b1[j] : 0.f;

    for (int k4 = 0; k4 < 24; ++k4) {
        int k = kbase + k4 * 4;
        float4 xv = *(const float4*)&xs[r * 388 + k];
        #pragma unroll
        for (int j = 0; j < 32; ++j) {
            const float* w = W1 + j * 384 + k;
            acc[j] += xv.x * w[0] + xv.y * w[1] + xv.z * w[2] + xv.w * w[3];
        }
    }
    #pragma unroll
    for (int j = 0; j < 32; ++j) part[tid * 36 + j] = acc[j];
    __syncthreads();

    if (tid < 64) {
        float fin[32];
        #pragma unroll
        for (int j = 0; j < 32; ++j)
            fin[j] = part[tid * 36 + j] + part[(64 + tid) * 36 + j] +
                     part[(128 + tid) * 36 + j] + part[(192 + tid) * 36 + j];
        float4* dst = (float4*)(pre1 + (size_t)(r0 + tid) * 32);
        #pragma unroll
        for (int j4 = 0; j4 < 8; ++j4)
            dst[j4] = make_float4(fin[j4 * 4 + 0], fin[j4 * 4 + 1], fin[j4 * 4 + 2], fin[j4 * 4 + 3]);
        #pragma unroll
        for (int j = 0; j < 32; ++j) part[tid * 36 + j] = fin[j];
    }
    __syncthreads();
    if (tid < 32) {
        float s = 0.f, sq = 0.f;
        for (int rr = 0; rr < 64; ++rr) {
            float v = part[rr * 36 + tid];
            s += v; sq += v * v;
        }
        atomicAdd(&stats1[tid], s);
        atomicAdd(&stats1[32 + tid], sq);
    }
}

// ---------------- kernel 2: h1 = relu(BN1(pre1)); pre2 = h1 @ W2^T + b2; BN2 stats ----------------
__global__ __launch_bounds__(256) void k_mlp2(const float* __restrict__ pre1,
                                              const float* __restrict__ stats1,
                                              const float* __restrict__ g1,
                                              const float* __restrict__ be1,
                                              const float* __restrict__ W2,
                                              const float* __restrict__ b2,
                                              float* __restrict__ pre2,
                                              float* __restrict__ stats2) {
    __shared__ __align__(16) float t2[256 * 36];
    const int tid = threadIdx.x;
    const size_t r = (size_t)blockIdx.x * 256 + tid;
    const float invB = 1.f / 16384.f;

    float p[32];
    const float4* pr = (const float4*)(pre1 + r * 32);
    #pragma unroll
    for (int j4 = 0; j4 < 8; ++j4) {
        float4 v = pr[j4];
        p[j4 * 4 + 0] = v.x; p[j4 * 4 + 1] = v.y; p[j4 * 4 + 2] = v.z; p[j4 * 4 + 3] = v.w;
    }
    float h1[32];
    #pragma unroll
    for (int j = 0; j < 32; ++j) {
        float mu = stats1[j] * invB;
        float va = stats1[32 + j] * invB - mu * mu;
        float sc = g1[j] * rsqrtf(va + EPSV);
        float v  = (p[j] - mu) * sc + be1[j];
        h1[j] = fmaxf(v, 0.f);
    }
    float acc[32];
    #pragma unroll
    for (int j = 0; j < 32; ++j) {
        const float* w = W2 + j * 32;
        float a0 = 0.f, a1 = 0.f, a2 = 0.f, a3 = 0.f;
        #pragma unroll
        for (int k = 0; k < 32; k += 4) {
            a0 = fmaf(h1[k + 0], w[k + 0], a0);
            a1 = fmaf(h1[k + 1], w[k + 1], a1);
            a2 = fmaf(h1[k + 2], w[k + 2], a2);
            a3 = fmaf(h1[k + 3], w[k + 3], a3);
        }
        acc[j] = b2[j] + ((a0 + a1) + (a2 + a3));
    }
    float4* dst = (float4*)(pre2 + r * 32);
    #pragma unroll
    for (int j4 = 0; j4 < 8; ++j4)
        dst[j4] = make_float4(acc[j4 * 4 + 0], acc[j4 * 4 + 1], acc[j4 * 4 + 2], acc[j4 * 4 + 3]);

    #pragma unroll
    for (int j = 0; j < 32; ++j) t2[tid * 36 + j] = acc[j];
    __syncthreads();
    if (tid < 32) {
        float s = 0.f, sq = 0.f;
        for (int rr = 0; rr < 256; ++rr) {
            float v = t2[rr * 36 + tid];
            s += v; sq += v * v;
        }
        atomicAdd(&stats2[tid], s);
        atomicAdd(&stats2[32 + tid], sq);
    }
}

// ---------------- kernel 3: BN2 -> ReLU -> m = h2@W3^T+b3 -> 26-step LSTM via MFMA ----------------
// 512 blocks x 256 threads; block = 32 rows (2 blocks/CU -> 2 waves/SIMD).
// Wave q owns u-block [16q,16q+16): N-tiles {i,f,g,o} at cols {q*16, 64+q*16, 128+q*16, 192+q*16}.
// B-fragments (weights) in VGPRs; h exchanged via double-buffered LDS; 1 barrier/step.
__global__ __launch_bounds__(256, 2) void k_lstm_mfma(
    const float* __restrict__ pre2, const float* __restrict__ stats2,
    const float* __restrict__ g2, const float* __restrict__ be2,
    const float* __restrict__ W3, const float* __restrict__ b3,
    const ushort* __restrict__ Wih_hi, const ushort* __restrict__ Wih_lo,
    const ushort* __restrict__ Wsum_hi, const ushort* __restrict__ Wsum_lo,
    const float* __restrict__ bsum, float* __restrict__ out)
{
    __shared__ __align__(16) ushort hhi[2][32][72];  // stride 72 bf16 = 144 B (16B-aligned rows)
    __shared__ __align__(16) ushort hlo[2][32][72];
    const int tid  = threadIdx.x;
    const int lane = tid & 63;
    const int l15  = lane & 15;
    const int lg   = lane >> 4;                       // 0..3
    const int q    = tid >> 6;                        // wave 0..3
    const int r0   = blockIdx.x * 32;
    const float invB = 1.f / 16384.f;

    // ---- MLP tail: m = relu(BN2(pre2)) @ W3^T + b3 for rows r0..r0+31; write hi/lo into buf 0
    {
        const int row = tid & 31;
        const int seg = tid >> 5;                     // u = seg*8 .. +8
        float h2[32];
        const float4* pr = (const float4*)(pre2 + (size_t)(r0 + row) * 32);
        #pragma unroll
        for (int j4 = 0; j4 < 8; ++j4) {
            float4 v = pr[j4];
            h2[j4 * 4 + 0] = v.x; h2[j4 * 4 + 1] = v.y;
            h2[j4 * 4 + 2] = v.z; h2[j4 * 4 + 3] = v.w;
        }
        #pragma unroll
        for (int j = 0; j < 32; ++j) {
            float mu = stats2[j] * invB;
            float va = stats2[32 + j] * invB - mu * mu;
            float sc = g2[j] * rsqrtf(va + EPSV);
            float v  = (h2[j] - mu) * sc + be2[j];
            h2[j] = fmaxf(v, 0.f);
        }
        #pragma unroll
        for (int uu = 0; uu < 8; ++uu) {
            int u = seg * 8 + uu;
            const float* w = W3 + u * 32;
            float a0 = 0.f, a1 = 0.f, a2 = 0.f, a3 = 0.f;
            #pragma unroll
            for (int k = 0; k < 32; k += 4) {
                a0 = fmaf(h2[k + 0], w[k + 0], a0);
                a1 = fmaf(h2[k + 1], w[k + 1], a1);
                a2 = fmaf(h2[k + 2], w[k + 2], a2);
                a3 = fmaf(h2[k + 3], w[k + 3], a3);
            }
            float m = b3[u] + ((a0 + a1) + (a2 + a3));
            ushort mh, ml; split_bf16(m, mh, ml);
            hhi[0][row][u] = mh;
            hlo[0][row][u] = ml;
        }
    }

    // ---- per-lane gate bias (cols j = nt*64 + q*16 + l15)
    float bias[4];
    #pragma unroll
    for (int nt = 0; nt < 4; ++nt) bias[nt] = bsum[nt * 64 + q * 16 + l15];

    float c[2][4];
    #pragma unroll
    for (int mt = 0; mt < 2; ++mt)
        #pragma unroll
        for (int rg = 0; rg < 4; ++rg) c[mt][rg] = 0.f;

    // ---- B fragments: lane supplies W[j = j0 + l15][k = kt*32 + lg*8 .. +8]
    bf16x8 Bhi[4][2], Blo[4][2];
    const size_t wofs = (size_t)(q * 16 + l15) * 64 + lg * 8;
    #pragma unroll
    for (int nt = 0; nt < 4; ++nt)
        #pragma unroll
        for (int kt = 0; kt < 2; ++kt) {
            Bhi[nt][kt] = *(const bf16x8*)(Wih_hi + (size_t)nt * 4096 + wofs + kt * 32);
            Blo[nt][kt] = *(const bf16x8*)(Wih_lo + (size_t)nt * 4096 + wofs + kt * 32);
        }

    __syncthreads();

    #pragma unroll 1
    for (int s = 0; s <= 25; ++s) {
        const int buf = s & 1, nbuf = buf ^ 1;
        f32x4 acc[2][4];
        #pragma unroll
        for (int mt = 0; mt < 2; ++mt)
            #pragma unroll
            for (int nt = 0; nt < 4; ++nt)
                acc[mt][nt] = (f32x4){bias[nt], bias[nt], bias[nt], bias[nt]};

        #pragma unroll
        for (int mt = 0; mt < 2; ++mt) {
            #pragma unroll
            for (int kt = 0; kt < 2; ++kt) {
                bf16x8 ahi = *(const bf16x8*)&hhi[buf][mt * 16 + l15][kt * 32 + lg * 8];
                bf16x8 alo = *(const bf16x8*)&hlo[buf][mt * 16 + l15][kt * 32 + lg * 8];
                #pragma unroll
                for (int nt = 0; nt < 4; ++nt) {
                    acc[mt][nt] = __builtin_amdgcn_mfma_f32_16x16x32_bf16(ahi, Bhi[nt][kt], acc[mt][nt], 0, 0, 0);
                    acc[mt][nt] = __builtin_amdgcn_mfma_f32_16x16x32_bf16(ahi, Blo[nt][kt], acc[mt][nt], 0, 0, 0);
                    acc[mt][nt] = __builtin_amdgcn_mfma_f32_16x16x32_bf16(alo, Bhi[nt][kt], acc[mt][nt], 0, 0, 0);
                }
            }
        }

        // ---- activations + state update; D layout: col = l15 (-> u), row = lg*4+rg (+16*mt)
        const int u = q * 16 + l15;
        #pragma unroll
        for (int mt = 0; mt < 2; ++mt) {
            #pragma unroll
            for (int rg = 0; rg < 4; ++rg) {
                int row = mt * 16 + lg * 4 + rg;
                float iv = acc[mt][0][rg], fv = acc[mt][1][rg];
                float gv = acc[mt][2][rg], ov = acc[mt][3][rg];
                float cc = sigm(fv) * c[mt][rg] + sigm(iv) * tanh_fast(gv);
                c[mt][rg] = cc;
                float hn = sigm(ov) * tanh_fast(cc);
                ushort hh, hl; split_bf16(hn, hh, hl);
                hhi[nbuf][row][u] = hh;
                hlo[nbuf][row][u] = hl;
                if (s >= 1)
                    out[(size_t)(r0 + row) * 1600 + (size_t)(s - 1) * 64 + u] = hn;
            }
        }

        if (s == 0) {  // switch B fragments from Wih to Wsum = Wih+Whh for self-feed steps
            #pragma unroll
            for (int nt = 0; nt < 4; ++nt)
                #pragma unroll
                for (int kt = 0; kt < 2; ++kt) {
                    Bhi[nt][kt] = *(const bf16x8*)(Wsum_hi + (size_t)nt * 4096 + wofs + kt * 32);
                    Blo[nt][kt] = *(const bf16x8*)(Wsum_lo + (size_t)nt * 4096 + wofs + kt * 32);
                }
        }
        __syncthreads();
    }
}

extern "C" void kernel_launch(void* const* d_in, const int* in_sizes, int n_in,
                              void* d_out, int out_size, void* d_ws, size_t ws_size,
                              hipStream_t stream) {
    const float* x0   = (const float*)d_in[0];
    const float* x1   = (const float*)d_in[1];
    const float* x2   = (const float*)d_in[2];
    const float* W1   = (const float*)d_in[3];
    const float* b1   = (const float*)d_in[4];
    const float* g1   = (const float*)d_in[5];
    const float* be1  = (const float*)d_in[6];
    const float* W2   = (const float*)d_in[7];
    const float* b2   = (const float*)d_in[8];
    const float* g2   = (const float*)d_in[9];
    const float* be2  = (const float*)d_in[10];
    const float* W3   = (const float*)d_in[11];
    const float* b3   = (const float*)d_in[12];
    const float* Wih  = (const float*)d_in[13];
    const float* Whh  = (const float*)d_in[14];
    const float* bih  = (const float*)d_in[15];
    const float* bhh  = (const float*)d_in[16];

    float* ws     = (float*)d_ws;
    float* pre1   = ws;                  // 524288 floats
    float* pre2   = ws + 524288;         // 524288 floats
    float* stats1 = ws + 1048576;        // 64
    float* stats2 = ws + 1048640;        // 64
    float* bsum   = ws + 1048704;        // 256
    ushort* ub    = (ushort*)(ws + 1048960);  // 16B-aligned
    ushort* Wih_hi  = ub;
    ushort* Wih_lo  = ub + 16384;
    ushort* Wsum_hi = ub + 32768;
    ushort* Wsum_lo = ub + 49152;

    hipMemsetAsync(stats1, 0, 128 * sizeof(float), stream);

    hipLaunchKernelGGL(k_prep, dim3(64), dim3(256), 0, stream,
                       Wih, Whh, bih, bhh, Wih_hi, Wih_lo, Wsum_hi, Wsum_lo, bsum);
    hipLaunchKernelGGL(k_mlp1, dim3(256), dim3(256), 0, stream, x0, x1, x2, W1, b1, pre1, stats1);
    hipLaunchKernelGGL(k_mlp2, dim3(64), dim3(256), 0, stream, pre1, stats1, g1, be1, W2, b2, pre2, stats2);
    hipLaunchKernelGGL(k_lstm_mfma, dim3(512), dim3(256), 0, stream,
                       pre2, stats2, g2, be2, W3, b3,
                       Wih_hi, Wih_lo, Wsum_hi, Wsum_lo, bsum, (float*)d_out);
}

// Round 4
// 124.627 us; speedup vs baseline: 5.0412x; 1.0891x over previous
//
#include <hip/hip_runtime.h>

// Predictor: MLP3 (Linear+BN(train)+ReLU x2, Linear) -> LSTM(64), 1 cond + 25 self-feed steps.
// B=16384, OUT=128 (x3 -> 384), HID=32, LSTM_H=64, NPRED=25. Output (B,25,64) fp32.
// All GEMMs via split-precision bf16 MFMA: P = A_hi*B_hi + A_hi*B_lo + A_lo*B_hi (fp32 accum).
// BN stats are BIT-DETERMINISTIC: per-wave partials to unique slots + fixed-order 1-block reduce
// (float atomics caused run-to-run divergence amplified by the chaotic 26-step recurrence).

#define EPSV 1e-5f

typedef __attribute__((ext_vector_type(8))) short bf16x8;
typedef __attribute__((ext_vector_type(4))) float f32x4;

__device__ __forceinline__ float rcp_f(float x) { return __builtin_amdgcn_rcpf(x); }
__device__ __forceinline__ float sigm(float x) { return rcp_f(1.f + __expf(-x)); }
__device__ __forceinline__ float tanh_fast(float x) {
    return 1.f - 2.f * rcp_f(__expf(2.f * x) + 1.f);  // saturates correctly at +-1
}
__device__ __forceinline__ void split_bf16(float x, ushort& hi, ushort& lo) {
    unsigned xb = __builtin_bit_cast(unsigned, x);
    hi = (ushort)(xb >> 16);
    float hif = __builtin_bit_cast(float, xb & 0xffff0000u);
    unsigned lb = __builtin_bit_cast(unsigned, x - hif);
    lo = (ushort)(lb >> 16);
}

// ---------------- kernel 0: split Wih/Wsum/W1/W2 into bf16 hi/lo; bsum ----------------
__global__ __launch_bounds__(256) void k_prep(
    const float* __restrict__ Wih, const float* __restrict__ Whh,
    const float* __restrict__ bih, const float* __restrict__ bhh,
    const float* __restrict__ W1, const float* __restrict__ W2,
    ushort* __restrict__ Wih_hi, ushort* __restrict__ Wih_lo,
    ushort* __restrict__ Wsum_hi, ushort* __restrict__ Wsum_lo,
    ushort* __restrict__ W1hi, ushort* __restrict__ W1lo,
    ushort* __restrict__ W2hi, ushort* __restrict__ W2lo,
    float* __restrict__ bsum)
{
    int i = blockIdx.x * 256 + threadIdx.x;
    ushort h, l;
    if (i < 16384) {
        float wi = Wih[i];
        float wsv = wi + Whh[i];
        split_bf16(wi, h, l);  Wih_hi[i] = h;  Wih_lo[i] = l;
        split_bf16(wsv, h, l); Wsum_hi[i] = h; Wsum_lo[i] = l;
    }
    if (i < 12288) { split_bf16(W1[i], h, l); W1hi[i] = h; W1lo[i] = l; }
    if (i < 1024)  { split_bf16(W2[i], h, l); W2hi[i] = h; W2lo[i] = l; }
    if (i < 256)   bsum[i] = bih[i] + bhh[i];
}

// ---------------- k_red: fixed-order BN-stats reduce -> scale/shift (deterministic) ----------------
// 1 block x 256 thr. part: [1024][32] sums, +32768: [1024][32] sumsqs.
__global__ __launch_bounds__(256) void k_red(const float* __restrict__ part,
                                             const float* __restrict__ g,
                                             const float* __restrict__ be,
                                             float* __restrict__ scsh) {
    __shared__ float rs[8][32], rq[8][32];
    const int t = threadIdx.x, ch = t & 31, sl = t >> 5;
    float s = 0.f, q = 0.f;
    #pragma unroll 4
    for (int i = 0; i < 128; ++i) {
        int b = sl * 128 + i;
        s += part[b * 32 + ch];
        q += part[32768 + b * 32 + ch];
    }
    rs[sl][ch] = s; rq[sl][ch] = q;
    __syncthreads();
    if (t < 32) {
        float ss = 0.f, qq = 0.f;
        #pragma unroll
        for (int k = 0; k < 8; ++k) { ss += rs[k][t]; qq += rq[k][t]; }
        float mu = ss * (1.f / 16384.f);
        float va = qq * (1.f / 16384.f) - mu * mu;
        float sc = g[t] * rsqrtf(va + EPSV);
        scsh[t] = sc; scsh[32 + t] = be[t] - mu * sc;
    }
}

// ---------------- kernel 1: pre = [x0|x1|x2] @ W1^T + b1 (MFMA), + BN1 partial stats ----------------
// 512 blocks x 256 thr; block = 32 rows; wave q: m0=(q&1)*16, n0=(q>>1)*16; K=384 = 12 kt.
__global__ __launch_bounds__(256) void k_mlp1(
    const float* __restrict__ x0, const float* __restrict__ x1, const float* __restrict__ x2,
    const ushort* __restrict__ W1hi, const ushort* __restrict__ W1lo,
    const float* __restrict__ b1,
    float* __restrict__ pre, float* __restrict__ st1p)
{
    __shared__ __align__(16) ushort xhi[32 * 392];
    __shared__ __align__(16) ushort xlo[32 * 392];
    const int tid = threadIdx.x;
    const int r0  = blockIdx.x * 32;

    for (int a = 0; a < 3; ++a) {
        const float* xp = (a == 0) ? x0 : (a == 1) ? x1 : x2;
        const float4* src = (const float4*)(xp + (size_t)r0 * 128);
        #pragma unroll
        for (int it = 0; it < 4; ++it) {
            int i = it * 256 + tid;        // 0..1023 float4s
            int row = i >> 5, c4 = i & 31;
            float4 v = src[i];
            ushort h0, l0, h1, l1, h2, l2, h3, l3;
            split_bf16(v.x, h0, l0); split_bf16(v.y, h1, l1);
            split_bf16(v.z, h2, l2); split_bf16(v.w, h3, l3);
            int ofs = row * 392 + a * 128 + c4 * 4;
            *(ushort4*)&xhi[ofs] = make_ushort4(h0, h1, h2, h3);
            *(ushort4*)&xlo[ofs] = make_ushort4(l0, l1, l2, l3);
        }
    }
    __syncthreads();

    const int lane = tid & 63, l15 = lane & 15, lg = lane >> 4, q = tid >> 6;
    const int m0 = (q & 1) * 16, n0 = (q >> 1) * 16;
    const float bias = b1[n0 + l15];
    f32x4 acc = {bias, bias, bias, bias};
    #pragma unroll
    for (int kt = 0; kt < 12; ++kt) {
        bf16x8 ahi = *(const bf16x8*)&xhi[(m0 + l15) * 392 + kt * 32 + lg * 8];
        bf16x8 alo = *(const bf16x8*)&xlo[(m0 + l15) * 392 + kt * 32 + lg * 8];
        bf16x8 bhi = *(const bf16x8*)(W1hi + (size_t)(n0 + l15) * 384 + kt * 32 + lg * 8);
        bf16x8 blo = *(const bf16x8*)(W1lo + (size_t)(n0 + l15) * 384 + kt * 32 + lg * 8);
        acc = __builtin_amdgcn_mfma_f32_16x16x32_bf16(ahi, bhi, acc, 0, 0, 0);
        acc = __builtin_amdgcn_mfma_f32_16x16x32_bf16(ahi, blo, acc, 0, 0, 0);
        acc = __builtin_amdgcn_mfma_f32_16x16x32_bf16(alo, bhi, acc, 0, 0, 0);
    }
    #pragma unroll
    for (int rg = 0; rg < 4; ++rg)
        pre[(size_t)(r0 + m0 + lg * 4 + rg) * 32 + n0 + l15] = acc[rg];
    // BN1 partials: wave-local fixed-order reduce, unique slot per (block, m-half, channel)
    float s  = (acc[0] + acc[1]) + (acc[2] + acc[3]);
    float sq = (acc[0] * acc[0] + acc[1] * acc[1]) + (acc[2] * acc[2] + acc[3] * acc[3]);
    s  += __shfl_xor(s, 16);  s  += __shfl_xor(s, 32);
    sq += __shfl_xor(sq, 16); sq += __shfl_xor(sq, 32);
    if (lg == 0) {
        int slot = (blockIdx.x * 2 + (q & 1)) * 32 + n0 + l15;
        st1p[slot] = s;
        st1p[32768 + slot] = sq;
    }
}

// ---------------- kernel 2: h1 = relu(BN1(pre)); pre = h1 @ W2^T + b2 IN-PLACE; BN2 partials ----------------
// 512 blocks x 256 thr; block = 32 rows; K=32 (1 kt).
__global__ __launch_bounds__(256) void k_mlp2(
    float* __restrict__ pre, const float* __restrict__ scsh1,
    const ushort* __restrict__ W2hi, const ushort* __restrict__ W2lo,
    const float* __restrict__ b2, float* __restrict__ st2p)
{
    __shared__ __align__(16) ushort hhi[32 * 40];
    __shared__ __align__(16) ushort hlo[32 * 40];
    __shared__ float bnsc[32], bnsh[32];
    const int tid = threadIdx.x;
    const int r0  = blockIdx.x * 32;

    if (tid < 32) { bnsc[tid] = scsh1[tid]; bnsh[tid] = scsh1[32 + tid]; }
    __syncthreads();
    {
        int row = tid >> 3, c4 = tid & 7;
        float4 v = ((const float4*)(pre + (size_t)r0 * 32))[tid];
        float e0 = fmaxf(fmaf(v.x, bnsc[c4 * 4 + 0], bnsh[c4 * 4 + 0]), 0.f);
        float e1 = fmaxf(fmaf(v.y, bnsc[c4 * 4 + 1], bnsh[c4 * 4 + 1]), 0.f);
        float e2 = fmaxf(fmaf(v.z, bnsc[c4 * 4 + 2], bnsh[c4 * 4 + 2]), 0.f);
        float e3 = fmaxf(fmaf(v.w, bnsc[c4 * 4 + 3], bnsh[c4 * 4 + 3]), 0.f);
        ushort h0, l0, h1, l1, h2, l2, h3, l3;
        split_bf16(e0, h0, l0); split_bf16(e1, h1, l1);
        split_bf16(e2, h2, l2); split_bf16(e3, h3, l3);
        int ofs = row * 40 + c4 * 4;
        *(ushort4*)&hhi[ofs] = make_ushort4(h0, h1, h2, h3);
        *(ushort4*)&hlo[ofs] = make_ushort4(l0, l1, l2, l3);
    }
    __syncthreads();

    const int lane = tid & 63, l15 = lane & 15, lg = lane >> 4, q = tid >> 6;
    const int m0 = (q & 1) * 16, n0 = (q >> 1) * 16;
    const float bias = b2[n0 + l15];
    f32x4 acc = {bias, bias, bias, bias};
    bf16x8 ahi = *(const bf16x8*)&hhi[(m0 + l15) * 40 + lg * 8];
    bf16x8 alo = *(const bf16x8*)&hlo[(m0 + l15) * 40 + lg * 8];
    bf16x8 bhi = *(const bf16x8*)(W2hi + (size_t)(n0 + l15) * 32 + lg * 8);
    bf16x8 blo = *(const bf16x8*)(W2lo + (size_t)(n0 + l15) * 32 + lg * 8);
    acc = __builtin_amdgcn_mfma_f32_16x16x32_bf16(ahi, bhi, acc, 0, 0, 0);
    acc = __builtin_amdgcn_mfma_f32_16x16x32_bf16(ahi, blo, acc, 0, 0, 0);
    acc = __builtin_amdgcn_mfma_f32_16x16x32_bf16(alo, bhi, acc, 0, 0, 0);

    #pragma unroll
    for (int rg = 0; rg < 4; ++rg)
        pre[(size_t)(r0 + m0 + lg * 4 + rg) * 32 + n0 + l15] = acc[rg];
    float s  = (acc[0] + acc[1]) + (acc[2] + acc[3]);
    float sq = (acc[0] * acc[0] + acc[1] * acc[1]) + (acc[2] * acc[2] + acc[3] * acc[3]);
    s  += __shfl_xor(s, 16);  s  += __shfl_xor(s, 32);
    sq += __shfl_xor(sq, 16); sq += __shfl_xor(sq, 32);
    if (lg == 0) {
        int slot = (blockIdx.x * 2 + (q & 1)) * 32 + n0 + l15;
        st2p[slot] = s;
        st2p[32768 + slot] = sq;
    }
}

// ---------------- kernel 3: BN2 -> ReLU -> m = h2@W3^T+b3 -> 26-step LSTM via MFMA ----------------
// 1024 blocks x 256 thr; block = 16 rows (4 blocks/CU -> 4 waves/SIMD).
__global__ __launch_bounds__(256, 4) void k_lstm(
    const float* __restrict__ pre, const float* __restrict__ scsh2,
    const float* __restrict__ W3, const float* __restrict__ b3,
    const ushort* __restrict__ Wih_hi, const ushort* __restrict__ Wih_lo,
    const ushort* __restrict__ Wsum_hi, const ushort* __restrict__ Wsum_lo,
    const float* __restrict__ bsum, float* __restrict__ out)
{
    __shared__ __align__(16) ushort hhi[2][16][72];
    __shared__ __align__(16) ushort hlo[2][16][72];
    __shared__ float bn2sc[32], bn2sh[32];
    const int tid  = threadIdx.x;
    const int lane = tid & 63, l15 = lane & 15, lg = lane >> 4, q = tid >> 6;
    const int r0   = blockIdx.x * 16;

    if (tid < 32) { bn2sc[tid] = scsh2[tid]; bn2sh[tid] = scsh2[32 + tid]; }
    __syncthreads();

    // ---- MLP tail: m = relu(BN2(pre)) @ W3^T + b3; thread (row=tid&15, seg=tid>>4) -> 4 u
    {
        const int row = tid & 15, seg = tid >> 4;
        float h2[32];
        const float4* pr = (const float4*)(pre + (size_t)(r0 + row) * 32);
        #pragma unroll
        for (int j4 = 0; j4 < 8; ++j4) {
            float4 v = pr[j4];
            h2[j4 * 4 + 0] = v.x; h2[j4 * 4 + 1] = v.y;
            h2[j4 * 4 + 2] = v.z; h2[j4 * 4 + 3] = v.w;
        }
        #pragma unroll
        for (int j = 0; j < 32; ++j) h2[j] = fmaxf(fmaf(h2[j], bn2sc[j], bn2sh[j]), 0.f);
        #pragma unroll
        for (int uu = 0; uu < 4; ++uu) {
            int u = seg * 4 + uu;
            const float* w = W3 + u * 32;
            float a0 = 0.f, a1 = 0.f, a2 = 0.f, a3 = 0.f;
            #pragma unroll
            for (int k = 0; k < 32; k += 4) {
                a0 = fmaf(h2[k + 0], w[k + 0], a0);
                a1 = fmaf(h2[k + 1], w[k + 1], a1);
                a2 = fmaf(h2[k + 2], w[k + 2], a2);
                a3 = fmaf(h2[k + 3], w[k + 3], a3);
            }
            float m = b3[u] + ((a0 + a1) + (a2 + a3));
            ushort mh, ml; split_bf16(m, mh, ml);
            hhi[0][row][u] = mh;
            hlo[0][row][u] = ml;
        }
    }

    float bias[4];
    #pragma unroll
    for (int nt = 0; nt < 4; ++nt) bias[nt] = bsum[nt * 64 + q * 16 + l15];
    float c[4] = {0.f, 0.f, 0.f, 0.f};

    bf16x8 Bhi[4][2], Blo[4][2];
    const size_t wofs = (size_t)(q * 16 + l15) * 64 + lg * 8;
    #pragma unroll
    for (int nt = 0; nt < 4; ++nt)
        #pragma unroll
        for (int kt = 0; kt < 2; ++kt) {
            Bhi[nt][kt] = *(const bf16x8*)(Wih_hi + (size_t)nt * 4096 + wofs + kt * 32);
            Blo[nt][kt] = *(const bf16x8*)(Wih_lo + (size_t)nt * 4096 + wofs + kt * 32);
        }
    __syncthreads();

    #pragma unroll 1
    for (int s = 0; s <= 25; ++s) {
        const int buf = s & 1, nbuf = buf ^ 1;
        f32x4 acc[4];
        #pragma unroll
        for (int nt = 0; nt < 4; ++nt)
            acc[nt] = (f32x4){bias[nt], bias[nt], bias[nt], bias[nt]};

        #pragma unroll
        for (int kt = 0; kt < 2; ++kt) {
            bf16x8 ahi = *(const bf16x8*)&hhi[buf][l15][kt * 32 + lg * 8];
            bf16x8 alo = *(const bf16x8*)&hlo[buf][l15][kt * 32 + lg * 8];
            #pragma unroll
            for (int nt = 0; nt < 4; ++nt) {
                acc[nt] = __builtin_amdgcn_mfma_f32_16x16x32_bf16(ahi, Bhi[nt][kt], acc[nt], 0, 0, 0);
                acc[nt] = __builtin_amdgcn_mfma_f32_16x16x32_bf16(ahi, Blo[nt][kt], acc[nt], 0, 0, 0);
                acc[nt] = __builtin_amdgcn_mfma_f32_16x16x32_bf16(alo, Bhi[nt][kt], acc[nt], 0, 0, 0);
            }
        }

        const int u = q * 16 + l15;
        #pragma unroll
        for (int rg = 0; rg < 4; ++rg) {
            int row = lg * 4 + rg;
            float iv = acc[0][rg], fv = acc[1][rg];
            float gv = acc[2][rg], ov = acc[3][rg];
            float cc = sigm(fv) * c[rg] + sigm(iv) * tanh_fast(gv);
            c[rg] = cc;
            float hn = sigm(ov) * tanh_fast(cc);
            ushort hh, hl; split_bf16(hn, hh, hl);
            hhi[nbuf][row][u] = hh;
            hlo[nbuf][row][u] = hl;
            if (s >= 1)
                out[(size_t)(r0 + row) * 1600 + (size_t)(s - 1) * 64 + u] = hn;
        }

        if (s == 0) {
            #pragma unroll
            for (int nt = 0; nt < 4; ++nt)
                #pragma unroll
                for (int kt = 0; kt < 2; ++kt) {
                    Bhi[nt][kt] = *(const bf16x8*)(Wsum_hi + (size_t)nt * 4096 + wofs + kt * 32);
                    Blo[nt][kt] = *(const bf16x8*)(Wsum_lo + (size_t)nt * 4096 + wofs + kt * 32);
                }
        }
        __syncthreads();
    }
}

extern "C" void kernel_launch(void* const* d_in, const int* in_sizes, int n_in,
                              void* d_out, int out_size, void* d_ws, size_t ws_size,
                              hipStream_t stream) {
    const float* x0   = (const float*)d_in[0];
    const float* x1   = (const float*)d_in[1];
    const float* x2   = (const float*)d_in[2];
    const float* W1   = (const float*)d_in[3];
    const float* b1   = (const float*)d_in[4];
    const float* g1   = (const float*)d_in[5];
    const float* be1  = (const float*)d_in[6];
    const float* W2   = (const float*)d_in[7];
    const float* b2   = (const float*)d_in[8];
    const float* g2   = (const float*)d_in[9];
    const float* be2  = (const float*)d_in[10];
    const float* W3   = (const float*)d_in[11];
    const float* b3   = (const float*)d_in[12];
    const float* Wih  = (const float*)d_in[13];
    const float* Whh  = (const float*)d_in[14];
    const float* bih  = (const float*)d_in[15];
    const float* bhh  = (const float*)d_in[16];

    float* ws    = (float*)d_ws;
    float* pre   = ws;                   // 524288 floats (pre1, then pre2 in-place)
    float* st1p  = ws + 524288;          // 65536 (32768 sums + 32768 sqs)
    float* st2p  = ws + 589824;          // 65536
    float* scsh1 = ws + 655360;          // 64
    float* scsh2 = ws + 655424;          // 64
    float* bsum  = ws + 655488;          // 256
    ushort* ub   = (ushort*)(ws + 655744);
    ushort* Wih_hi  = ub;                // 16384
    ushort* Wih_lo  = ub + 16384;
    ushort* Wsum_hi = ub + 32768;
    ushort* Wsum_lo = ub + 49152;
    ushort* W1hi    = ub + 65536;        // 12288
    ushort* W1lo    = ub + 77824;
    ushort* W2hi    = ub + 90112;        // 1024
    ushort* W2lo    = ub + 91136;        // end 92160 (~2.7 MB total ws use)

    hipLaunchKernelGGL(k_prep, dim3(64), dim3(256), 0, stream,
                       Wih, Whh, bih, bhh, W1, W2,
                       Wih_hi, Wih_lo, Wsum_hi, Wsum_lo, W1hi, W1lo, W2hi, W2lo, bsum);
    hipLaunchKernelGGL(k_mlp1, dim3(512), dim3(256), 0, stream,
                       x0, x1, x2, W1hi, W1lo, b1, pre, st1p);
    hipLaunchKernelGGL(k_red, dim3(1), dim3(256), 0, stream, st1p, g1, be1, scsh1);
    hipLaunchKernelGGL(k_mlp2, dim3(512), dim3(256), 0, stream,
                       pre, scsh1, W2hi, W2lo, b2, st2p);
    hipLaunchKernelGGL(k_red, dim3(1), dim3(256), 0, stream, st2p, g2, be2, scsh2);
    hipLaunchKernelGGL(k_lstm, dim3(1024), dim3(256), 0, stream,
                       pre, scsh2, W3, b3,
                       Wih_hi, Wih_lo, Wsum_hi, Wsum_lo, bsum, (float*)d_out);
}